// Round 11
// baseline (1537.245 us; speedup 1.0000x reference)
//
#include <hip/hip_runtime.h>
#include <hip/hip_bf16.h>
#include <cstdint>
#include <cstddef>

#define IN_DIM 4096
#define OUT_DIM 2048
#define NEXP 5      // K+1 experts
#define KEXP 4
#define RDIM 4096
#define BATCH 4096

typedef __hip_bfloat16 bf16;
typedef __attribute__((ext_vector_type(8))) short bf16x8;
typedef __attribute__((ext_vector_type(16))) float f32x16;
typedef __attribute__((ext_vector_type(8))) unsigned short u16x8;
typedef __attribute__((ext_vector_type(4))) unsigned short u16x4;

typedef const __attribute__((address_space(1))) unsigned int* as1p;
typedef __attribute__((address_space(3))) unsigned int* as3p;

__device__ __forceinline__ unsigned short f2bf(float x) {
  union { __hip_bfloat16 h; unsigned short u; } cv;
  cv.h = __float2bfloat16(x);
  return cv.u;
}

// ---------------- fp32 -> bf16 conversion, 8 elems/thread ----------------
__global__ __launch_bounds__(256) void cvt_kernel(const float* __restrict__ in,
                                                  unsigned short* __restrict__ out,
                                                  int n8) {
  int i = blockIdx.x * 256 + threadIdx.x;
  if (i >= n8) return;
  const float4* p = (const float4*)in;
  float4 a = p[(size_t)i * 2];
  float4 b = p[(size_t)i * 2 + 1];
  u16x8 v;
  v[0] = f2bf(a.x); v[1] = f2bf(a.y); v[2] = f2bf(a.z); v[3] = f2bf(a.w);
  v[4] = f2bf(b.x); v[5] = f2bf(b.y); v[6] = f2bf(b.z); v[7] = f2bf(b.w);
  *(u16x8*)(out + (size_t)i * 8) = v;
}

// ------------- transpose-convert: in (NI,NO) fp32 -> out (NO,NI) bf16, batched z -------------
__global__ __launch_bounds__(256) void tcvt_kernel(const float* __restrict__ in,
                                                   unsigned short* __restrict__ out,
                                                   int NI, int NO) {
  __shared__ float tile[32][33];
  const float* inz = in + (size_t)blockIdx.z * NI * NO;
  unsigned short* outz = out + (size_t)blockIdx.z * NI * NO;
  int i0 = blockIdx.y * 32;
  int o0 = blockIdx.x * 32;
  int t = threadIdx.x;
  int ri = t >> 3, ro = (t & 7) << 2;
  float4 v = *(const float4*)(inz + (size_t)(i0 + ri) * NO + o0 + ro);
  tile[ri][ro] = v.x; tile[ri][ro + 1] = v.y; tile[ri][ro + 2] = v.z; tile[ri][ro + 3] = v.w;
  __syncthreads();
  int wo = t >> 3, wi = (t & 7) << 2;
  u16x4 w;
  w[0] = f2bf(tile[wi][wo]);
  w[1] = f2bf(tile[wi + 1][wo]);
  w[2] = f2bf(tile[wi + 2][wo]);
  w[3] = f2bf(tile[wi + 3][wo]);
  *(u16x4*)(outz + (size_t)(o0 + wo) * NI + i0 + wi) = w;
}

__device__ __forceinline__ void gload16(const bf16* g, bf16* l) {
  __builtin_amdgcn_global_load_lds((as1p)g, (as3p)l, 16, 0, 0);
}

template <int N> __device__ __forceinline__ void vwait() {
  if constexpr (N == 0) asm volatile("s_waitcnt vmcnt(0)" ::: "memory");
  else if constexpr (N == 2) asm volatile("s_waitcnt vmcnt(2)" ::: "memory");
  else if constexpr (N == 4) asm volatile("s_waitcnt vmcnt(4)" ::: "memory");
}

// 32x32x16 fragments: A/B lane l holds row/col (l&31), k = (l>>5)*8 + j.
// READ_A: 2 row-frags per half (rows (2*a2+wr)*32), 4 k-slices each.
#define READ_A(buf, mh)                                                  \
  do {                                                                   \
    const bf16* _pa = ldsA + (buf) * 16384 + (mh) * 8192;                \
    _Pragma("unroll") for (int a2 = 0; a2 < 2; ++a2) {                   \
      _Pragma("unroll") for (int ks = 0; ks < 4; ++ks) {                 \
        afr[a2][ks] = *(const bf16x8*)(_pa + aOff[a2][ks]);              \
      }                                                                  \
    }                                                                    \
  } while (0)

// READ_B: 1 col-frag per half (local col wc*32), 4 k-slices.
#define READ_B(buf, nh)                                                  \
  do {                                                                   \
    const bf16* _pb = ldsB + (buf) * 16384 + (nh) * 8192;                \
    _Pragma("unroll") for (int ks = 0; ks < 4; ++ks) {                   \
      bfr[nh][ks] = *(const bf16x8*)(_pb + bOff[ks]);                    \
    }                                                                    \
  } while (0)

#define QMFMA(mh, nh)                                                            \
  do {                                                                           \
    __builtin_amdgcn_s_setprio(1);                                               \
    _Pragma("unroll") for (int ks = 0; ks < 4; ++ks) {                           \
      _Pragma("unroll") for (int a2 = 0; a2 < 2; ++a2) {                         \
        acc[(mh) * 2 + a2][nh] = __builtin_amdgcn_mfma_f32_32x32x16_bf16(        \
            afr[a2][ks], bfr[nh][ks], acc[(mh) * 2 + a2][nh], 0, 0, 0);          \
      }                                                                          \
    }                                                                            \
    __builtin_amdgcn_s_setprio(0);                                               \
  } while (0)

#define BAR() __builtin_amdgcn_s_barrier()

// ---------- 256x256 kernel (R6 4-phase schedule, 32x32x16 MFMA) ----------
// EPI 0: C = bf16(acc); EPI 1: C = bf16(silu(acc+bias));
// EPI 2: p = acc + bias; d = AUX - p; accum[row] += d^2, accum[B+row] += |d|
template <int EPI>
__global__ __launch_bounds__(512, 2) void gemm8p(
    const bf16* __restrict__ A, int lda, long long aZ,
    const bf16* __restrict__ B, int ldb, long long bZ,
    int Kdim,
    unsigned short* __restrict__ C, int ldc, long long cZ,
    const float* __restrict__ bias,
    const bf16* __restrict__ AUX, int ldaux, long long auxZ,
    float* __restrict__ accum,
    int gx, int gxy, int nwg8) {
  extern __shared__ __align__(16) bf16 lds[];
  bf16* ldsA = lds;            // 2 bufs x (2 halves x 128r x 64c)
  bf16* ldsB = lds + 32768;

  int flat = blockIdx.x;
  int wg = (flat & 7) * nwg8 + (flat >> 3);
  int z = wg / gxy;
  int r0 = wg - z * gxy;
  int by = r0 / gx;
  int bx = r0 - by * gx;
  int rowBase = by * 256, colBase = bx * 256;

  int tid = threadIdx.x;
  int wave = tid >> 6, lane = tid & 63;
  int wr = wave >> 2, wc = wave & 3;

  const bf16* Ab = A + (long long)z * aZ + (long long)rowBase * lda;
  const bf16* Bb = B + (long long)z * bZ + (long long)colBase * ldb;

  int rl = tid >> 3;
  int cg8 = ((tid & 7) ^ (rl & 7)) << 3;
  int srcA = rl * lda + cg8;
  int srcB = rl * ldb + cg8;
  int dstOfs = wave * 512;

  int aOff[2][4], bOff[4];
#pragma unroll
  for (int a2 = 0; a2 < 2; ++a2) {
    int rA = (2 * a2 + wr) * 32 + (lane & 31);           // 0..127
#pragma unroll
    for (int ks = 0; ks < 4; ++ks) {
      int g = ks * 2 + (lane >> 5);
      aOff[a2][ks] = rA * 64 + ((g ^ (rA & 7)) << 3);
    }
  }
  {
    int rB = wc * 32 + (lane & 31);                      // 0..127 (both halves)
#pragma unroll
    for (int ks = 0; ks < 4; ++ks) {
      int g = ks * 2 + (lane >> 5);
      bOff[ks] = rB * 64 + ((g ^ (rB & 7)) << 3);
    }
  }

  f32x16 acc[4][2] = {};
  bf16x8 afr[2][4], bfr[2][4];

  auto stA = [&](int buf, int hh, int kt) {
    const bf16* s = Ab + (long long)(hh * 128) * lda + kt * 64;
    bf16* d = ldsA + buf * 16384 + hh * 8192 + dstOfs;
    gload16(s + srcA, d);
    gload16(s + srcA + 64 * lda, d + 4096);
  };
  auto stB = [&](int buf, int hh, int kt) {
    const bf16* s = Bb + (long long)(hh * 128) * ldb + kt * 64;
    bf16* d = ldsB + buf * 16384 + hh * 8192 + dstOfs;
    gload16(s + srcB, d);
    gload16(s + srcB + 64 * ldb, d + 4096);
  };

  int NT = Kdim >> 6;
  int cur = 0;

  stA(0, 0, 0); stB(0, 0, 0); stB(0, 1, 0); stA(0, 1, 0);
  vwait<4>();
  BAR();

  for (int t = 0; t < NT - 1; ++t) {
    int nb = cur ^ 1;
    READ_A(cur, 0);
    READ_B(cur, 0);
    stA(nb, 0, t + 1);
    vwait<4>();
    BAR();
    QMFMA(0, 0);
    READ_B(cur, 1);
    stB(nb, 0, t + 1);
    vwait<4>();
    BAR();
    QMFMA(0, 1);
    READ_A(cur, 1);
    stB(nb, 1, t + 1);
    BAR();
    QMFMA(1, 1);
    stA(nb, 1, t + 1);
    vwait<4>();
    BAR();
    QMFMA(1, 0);
    cur = nb;
  }

  READ_A(cur, 0);
  READ_B(cur, 0);
  vwait<2>();
  BAR();
  QMFMA(0, 0);
  READ_B(cur, 1);
  vwait<0>();
  BAR();
  QMFMA(0, 1);
  READ_A(cur, 1);
  QMFMA(1, 1);
  QMFMA(1, 0);

  // C/D layout (m74/m101): col = lane&31, row = (reg&3) + 8*(reg>>2) + 4*(lane>>5)
  if constexpr (EPI == 2) {
    const bf16* AUXb = AUX + (long long)z * auxZ;
#pragma unroll
    for (int fa = 0; fa < 4; ++fa) {
      int rbase = rowBase + (fa >> 1) * 128 + (2 * (fa & 1) + wr) * 32 + ((lane >> 5) << 2);
#pragma unroll
      for (int reg = 0; reg < 16; ++reg) {
        int row = rbase + (reg & 3) + ((reg >> 2) << 3);
        float ssq = 0.f, sab = 0.f;
#pragma unroll
        for (int b2 = 0; b2 < 2; ++b2) {
          int col = colBase + (b2 * 4 + wc) * 32 + (lane & 31);
          float p = acc[fa][b2][reg] + bias[col];
          float d = __bfloat162float(AUXb[(long long)row * ldaux + col]) - p;
          ssq += d * d;
          sab += fabsf(d);
        }
#pragma unroll
        for (int off = 1; off < 32; off <<= 1) {
          ssq += __shfl_xor(ssq, off);
          sab += __shfl_xor(sab, off);
        }
        if ((lane & 31) == 0) {
          atomicAdd(&accum[row], ssq);
          atomicAdd(&accum[BATCH + row], sab);
        }
      }
    }
  } else {
    unsigned short* Cb = C + (long long)z * cZ;
#pragma unroll
    for (int fa = 0; fa < 4; ++fa) {
      int rbase = rowBase + (fa >> 1) * 128 + (2 * (fa & 1) + wr) * 32 + ((lane >> 5) << 2);
#pragma unroll
      for (int b2 = 0; b2 < 2; ++b2) {
        int col = colBase + (b2 * 4 + wc) * 32 + (lane & 31);
#pragma unroll
        for (int reg = 0; reg < 16; ++reg) {
          int row = rbase + (reg & 3) + ((reg >> 2) << 3);
          float v = acc[fa][b2][reg];
          if constexpr (EPI == 1) {
            v += bias[col];
            v = v / (1.f + __expf(-v));
          }
          Cb[(long long)row * ldc + col] = f2bf(v);
        }
      }
    }
  }
}

// ---------- fused dual-B kernel: g = silu(x W1^T) * (x W3^T), 32x32x16 ----------
#define READ_BX(dst, base, buf)                                          \
  do {                                                                   \
    const bf16* _pb = (base) + (buf) * 8192;                             \
    _Pragma("unroll") for (int ks = 0; ks < 4; ++ks) {                   \
      dst[ks] = *(const bf16x8*)(_pb + bOff[ks]);                        \
    }                                                                    \
  } while (0)

#define QMFMA_D(ACC, mh, BF)                                                     \
  do {                                                                           \
    __builtin_amdgcn_s_setprio(1);                                               \
    _Pragma("unroll") for (int ks = 0; ks < 4; ++ks) {                           \
      _Pragma("unroll") for (int a2 = 0; a2 < 2; ++a2) {                         \
        ACC[(mh) * 2 + a2] = __builtin_amdgcn_mfma_f32_32x32x16_bf16(            \
            afr[a2][ks], BF[ks], ACC[(mh) * 2 + a2], 0, 0, 0);                   \
      }                                                                          \
    }                                                                            \
    __builtin_amdgcn_s_setprio(0);                                               \
  } while (0)

__global__ __launch_bounds__(512, 2) void gemm_dual(
    const bf16* __restrict__ A,
    const bf16* __restrict__ W1b, const bf16* __restrict__ W3b,
    unsigned short* __restrict__ G,
    int gx, int gxy, int nwg8) {
  extern __shared__ __align__(16) bf16 lds[];
  bf16* ldsA = lds;              // 2 bufs x 16384
  bf16* ldsB1 = lds + 32768;     // 2 bufs x 8192
  bf16* ldsB3 = lds + 49152;     // 2 bufs x 8192

  int flat = blockIdx.x;
  int wg = (flat & 7) * nwg8 + (flat >> 3);
  int z = wg / gxy;
  int r0 = wg - z * gxy;
  int by = r0 / gx;
  int bx = r0 - by * gx;
  int rowBase = by * 256, colBase = bx * 128;

  int tid = threadIdx.x;
  int wave = tid >> 6, lane = tid & 63;
  int wr = wave >> 2, wc = wave & 3;

  const bf16* Ab = A + (long long)rowBase * IN_DIM;
  const bf16* B1b = W1b + (long long)z * OUT_DIM * IN_DIM + (long long)colBase * IN_DIM;
  const bf16* B3b = W3b + (long long)z * OUT_DIM * IN_DIM + (long long)colBase * IN_DIM;

  int rl = tid >> 3;
  int cg8 = ((tid & 7) ^ (rl & 7)) << 3;
  int src = rl * IN_DIM + cg8;
  int dstOfs = wave * 512;

  int aOff[2][4], bOff[4];
#pragma unroll
  for (int a2 = 0; a2 < 2; ++a2) {
    int rA = (2 * a2 + wr) * 32 + (lane & 31);
#pragma unroll
    for (int ks = 0; ks < 4; ++ks) {
      int g = ks * 2 + (lane >> 5);
      aOff[a2][ks] = rA * 64 + ((g ^ (rA & 7)) << 3);
    }
  }
  {
    int rB = wc * 32 + (lane & 31);                      // 0..127
#pragma unroll
    for (int ks = 0; ks < 4; ++ks) {
      int g = ks * 2 + (lane >> 5);
      bOff[ks] = rB * 64 + ((g ^ (rB & 7)) << 3);
    }
  }

  f32x16 acc1[4] = {};
  f32x16 acc2[4] = {};
  bf16x8 afr[2][4], b1fr[4], b3fr[4];

  auto stA = [&](int buf, int hh, int kt) {
    const bf16* s = Ab + (long long)(hh * 128) * IN_DIM + kt * 64;
    bf16* d = ldsA + buf * 16384 + hh * 8192 + dstOfs;
    gload16(s + src, d);
    gload16(s + src + 64 * IN_DIM, d + 4096);
  };
  auto stB1 = [&](int buf, int kt) {
    const bf16* s = B1b + kt * 64;
    bf16* d = ldsB1 + buf * 8192 + dstOfs;
    gload16(s + src, d);
    gload16(s + src + 64 * IN_DIM, d + 4096);
  };
  auto stB3 = [&](int buf, int kt) {
    const bf16* s = B3b + kt * 64;
    bf16* d = ldsB3 + buf * 8192 + dstOfs;
    gload16(s + src, d);
    gload16(s + src + 64 * IN_DIM, d + 4096);
  };

  const int NT = IN_DIM >> 6;
  int cur = 0;

  stA(0, 0, 0); stB1(0, 0); stB3(0, 0); stA(0, 1, 0);
  vwait<4>();
  BAR();

  for (int t = 0; t < NT - 1; ++t) {
    int nb = cur ^ 1;
    READ_A(cur, 0);
    READ_BX(b1fr, ldsB1, cur);
    stA(nb, 0, t + 1);
    vwait<4>();
    BAR();
    QMFMA_D(acc1, 0, b1fr);
    READ_BX(b3fr, ldsB3, cur);
    stB1(nb, t + 1);
    vwait<4>();
    BAR();
    QMFMA_D(acc2, 0, b3fr);
    READ_A(cur, 1);
    stB3(nb, t + 1);
    BAR();
    QMFMA_D(acc1, 1, b1fr);
    stA(nb, 1, t + 1);
    vwait<4>();
    BAR();
    QMFMA_D(acc2, 1, b3fr);
    cur = nb;
  }

  READ_A(cur, 0);
  READ_BX(b1fr, ldsB1, cur);
  vwait<2>();
  BAR();
  QMFMA_D(acc1, 0, b1fr);
  READ_BX(b3fr, ldsB3, cur);
  vwait<0>();
  BAR();
  QMFMA_D(acc2, 0, b3fr);
  READ_A(cur, 1);
  QMFMA_D(acc1, 1, b1fr);
  QMFMA_D(acc2, 1, b3fr);

  // epilogue: g = silu(acc1) * acc2
  unsigned short* Gb = G + (long long)z * OUT_DIM;
  int col = colBase + wc * 32 + (lane & 31);
#pragma unroll
  for (int fa = 0; fa < 4; ++fa) {
    int rbase = rowBase + (fa >> 1) * 128 + (2 * (fa & 1) + wr) * 32 + ((lane >> 5) << 2);
#pragma unroll
    for (int reg = 0; reg < 16; ++reg) {
      int row = rbase + (reg & 3) + ((reg >> 2) << 3);
      float v1 = acc1[fa][reg], v2 = acc2[fa][reg];
      float g = v2 * (v1 / (1.f + __expf(-v1)));
      Gb[(long long)row * (NEXP * OUT_DIM) + col] = f2bf(g);
    }
  }
}

__global__ void zero_accum(float* a) {
  int i = blockIdx.x * 256 + threadIdx.x;
  if (i < 2 * BATCH) a[i] = 0.f;
}

__global__ void finalize_kernel(const float* __restrict__ accum, float* __restrict__ out) {
  int b = blockIdx.x * 256 + threadIdx.x;
  if (b < BATCH) {
    out[b] = sqrtf(accum[b]);
    out[BATCH + b] = accum[BATCH + b] * (1.f / IN_DIM);
  }
}

extern "C" void kernel_launch(void* const* d_in, const int* in_sizes, int n_in,
                              void* d_out, int out_size, void* d_ws, size_t ws_size,
                              hipStream_t stream) {
  const float* x    = (const float*)d_in[0];
  const float* W1   = (const float*)d_in[1];
  const float* W3   = (const float*)d_in[2];
  const float* W2   = (const float*)d_in[3];
  const float* fc1w = (const float*)d_in[4];
  const float* fc1b = (const float*)d_in[5];
  const float* fc2w = (const float*)d_in[6];
  const float* fc2b = (const float*)d_in[7];
  float* out = (float*)d_out;

  char* ws = (char*)d_ws;
  size_t off = 0;
  auto alloc = [&](size_t bytes) {
    char* p = ws + off;
    off += (bytes + 255) & ~(size_t)255;
    return p;
  };
  bf16* xb   = (bf16*)alloc((size_t)BATCH * IN_DIM * 2);
  bf16* w1b  = (bf16*)alloc((size_t)NEXP * OUT_DIM * IN_DIM * 2);
  bf16* w3b  = (bf16*)alloc((size_t)NEXP * OUT_DIM * IN_DIM * 2);
  bf16* w2b0 = (bf16*)alloc((size_t)IN_DIM * OUT_DIM * 2);
  bf16* w2t  = (bf16*)alloc((size_t)KEXP * OUT_DIM * IN_DIM * 2);
  bf16* f1b  = (bf16*)alloc((size_t)RDIM * IN_DIM * KEXP * 2);
  bf16* f2b  = (bf16*)alloc((size_t)IN_DIM * RDIM * 2);
  bf16* gbuf = (bf16*)alloc((size_t)BATCH * NEXP * OUT_DIM * 2);
  bf16* scratch = (bf16*)alloc((size_t)RDIM * KEXP * OUT_DIM * 2);   // Pcat (R x 8192)
  bf16* o0   = (bf16*)alloc((size_t)BATCH * IN_DIM * 2);
  bf16* hbuf = (bf16*)alloc((size_t)BATCH * RDIM * 2);
  float* accum = (float*)alloc((size_t)2 * BATCH * 4);
  if (off > ws_size) return;

  bf16* Pcat = scratch;

  auto cvt = [&](const float* in, bf16* outp, size_t n) {
    int n8 = (int)(n / 8);
    cvt_kernel<<<(n8 + 255) / 256, 256, 0, stream>>>(in, (unsigned short*)outp, n8);
  };
  cvt(x,    xb,   (size_t)BATCH * IN_DIM);
  cvt(W1,   w1b,  (size_t)NEXP * OUT_DIM * IN_DIM);
  cvt(W3,   w3b,  (size_t)NEXP * OUT_DIM * IN_DIM);
  cvt(W2,   w2b0, (size_t)IN_DIM * OUT_DIM);          // expert 0 (i,o)
  cvt(fc1w, f1b,  (size_t)RDIM * IN_DIM * KEXP);
  cvt(fc2w, f2b,  (size_t)IN_DIM * RDIM);
  // W2[1..4]: (i,o) fp32 -> (o,i) bf16
  tcvt_kernel<<<dim3(OUT_DIM / 32, IN_DIM / 32, KEXP), 256, 0, stream>>>(
      W2 + (size_t)IN_DIM * OUT_DIM, (unsigned short*)w2t, IN_DIM, OUT_DIM);

  const size_t LDSB = 131072;

  // stage 1 (fused): g = silu(x W1^T) * (x W3^T)
  {
    int gx = OUT_DIM / 128, gxy = gx * (BATCH / 256), nwg = gxy * NEXP;  // 1280
    gemm_dual<<<nwg, 512, LDSB, stream>>>(
        xb, w1b, w3b, (unsigned short*)gbuf, gx, gxy, nwg / 8);
  }
  // o0 = g_0 W2[0]^T
  {
    int gx = IN_DIM / 256, gxy = gx * (BATCH / 256), nwg = gxy;
    gemm8p<0><<<nwg, 512, LDSB, stream>>>(
        gbuf, NEXP * OUT_DIM, 0LL,
        w2b0, OUT_DIM, 0LL,
        OUT_DIM,
        (unsigned short*)o0, IN_DIM, 0LL,
        nullptr, nullptr, 0, 0LL, nullptr,
        gx, gxy, nwg / 8);
  }
  // P_k = F_k W2[k]  (R x 2048 each, stored side-by-side in Pcat, ldc 8192)
  {
    int gx = OUT_DIM / 256, gxy = gx * (RDIM / 256), nwg = gxy * KEXP;
    gemm8p<0><<<nwg, 512, LDSB, stream>>>(
        f1b, KEXP * IN_DIM, (long long)IN_DIM,
        w2t, IN_DIM, (long long)OUT_DIM * IN_DIM,
        IN_DIM,
        (unsigned short*)Pcat, KEXP * OUT_DIM, (long long)OUT_DIM,
        nullptr, nullptr, 0, 0LL, nullptr,
        gx, gxy, nwg / 8);
  }
  // fc1': h = silu(g[:,1:,:] Pcat^T + b)   (K = 8192)
  {
    int gx = RDIM / 256, gxy = gx * (BATCH / 256), nwg = gxy;
    gemm8p<1><<<nwg, 512, LDSB, stream>>>(
        gbuf + OUT_DIM, NEXP * OUT_DIM, 0LL,
        Pcat, KEXP * OUT_DIM, 0LL,
        KEXP * OUT_DIM,
        (unsigned short*)hbuf, RDIM, 0LL,
        fc1b, nullptr, 0, 0LL, nullptr,
        gx, gxy, nwg / 8);
  }
  // fc2 + diff-reduce vs o0
  zero_accum<<<(2 * BATCH + 255) / 256, 256, 0, stream>>>(accum);
  {
    int gx = IN_DIM / 256, gxy = gx * (BATCH / 256), nwg = gxy;
    gemm8p<2><<<nwg, 512, LDSB, stream>>>(
        hbuf, RDIM, 0LL,
        f2b, RDIM, 0LL,
        RDIM,
        nullptr, 0, 0LL,
        fc2b, o0, IN_DIM, 0LL, accum,
        gx, gxy, nwg / 8);
  }
  finalize_kernel<<<(BATCH + 255) / 256, 256, 0, stream>>>(accum, out);
}

// Round 12
// 1366.989 us; speedup vs baseline: 1.1245x; 1.1245x over previous
//
#include <hip/hip_runtime.h>
#include <hip/hip_bf16.h>
#include <cstdint>
#include <cstddef>

#define IN_DIM 4096
#define OUT_DIM 2048
#define NEXP 5      // K+1 experts
#define KEXP 4
#define RDIM 4096
#define BATCH 4096

typedef __hip_bfloat16 bf16;
typedef __attribute__((ext_vector_type(8))) short bf16x8;
typedef __attribute__((ext_vector_type(4))) float f32x4;
typedef __attribute__((ext_vector_type(8))) unsigned short u16x8;
typedef __attribute__((ext_vector_type(4))) unsigned short u16x4;

typedef const __attribute__((address_space(1))) unsigned int* as1p;
typedef __attribute__((address_space(3))) unsigned int* as3p;

__device__ __forceinline__ unsigned short f2bf(float x) {
  union { __hip_bfloat16 h; unsigned short u; } cv;
  cv.h = __float2bfloat16(x);
  return cv.u;
}

// ---------------- fp32 -> bf16 conversion, 8 elems/thread ----------------
__global__ __launch_bounds__(256) void cvt_kernel(const float* __restrict__ in,
                                                  unsigned short* __restrict__ out,
                                                  int n8) {
  int i = blockIdx.x * 256 + threadIdx.x;
  if (i >= n8) return;
  const float4* p = (const float4*)in;
  float4 a = p[(size_t)i * 2];
  float4 b = p[(size_t)i * 2 + 1];
  u16x8 v;
  v[0] = f2bf(a.x); v[1] = f2bf(a.y); v[2] = f2bf(a.z); v[3] = f2bf(a.w);
  v[4] = f2bf(b.x); v[5] = f2bf(b.y); v[6] = f2bf(b.z); v[7] = f2bf(b.w);
  *(u16x8*)(out + (size_t)i * 8) = v;
}

// ------------- transpose-convert: in (NI,NO) fp32 -> out (NO,NI) bf16, batched z -------------
__global__ __launch_bounds__(256) void tcvt_kernel(const float* __restrict__ in,
                                                   unsigned short* __restrict__ out,
                                                   int NI, int NO) {
  __shared__ float tile[32][33];
  const float* inz = in + (size_t)blockIdx.z * NI * NO;
  unsigned short* outz = out + (size_t)blockIdx.z * NI * NO;
  int i0 = blockIdx.y * 32;
  int o0 = blockIdx.x * 32;
  int t = threadIdx.x;
  int ri = t >> 3, ro = (t & 7) << 2;
  float4 v = *(const float4*)(inz + (size_t)(i0 + ri) * NO + o0 + ro);
  tile[ri][ro] = v.x; tile[ri][ro + 1] = v.y; tile[ri][ro + 2] = v.z; tile[ri][ro + 3] = v.w;
  __syncthreads();
  int wo = t >> 3, wi = (t & 7) << 2;
  u16x4 w;
  w[0] = f2bf(tile[wi][wo]);
  w[1] = f2bf(tile[wi + 1][wo]);
  w[2] = f2bf(tile[wi + 2][wo]);
  w[3] = f2bf(tile[wi + 3][wo]);
  *(u16x4*)(outz + (size_t)(o0 + wo) * NI + i0 + wi) = w;
}

__device__ __forceinline__ void gload16(const bf16* g, bf16* l) {
  __builtin_amdgcn_global_load_lds((as1p)g, (as3p)l, 16, 0, 0);
}

template <int N> __device__ __forceinline__ void vwait() {
  if constexpr (N == 0) asm volatile("s_waitcnt vmcnt(0)" ::: "memory");
  else if constexpr (N == 2) asm volatile("s_waitcnt vmcnt(2)" ::: "memory");
  else if constexpr (N == 4) asm volatile("s_waitcnt vmcnt(4)" ::: "memory");
}

#define READ_A(buf, mh)                                              \
  do {                                                               \
    const bf16* _pa = ldsA + (buf) * 16384 + (mh) * 8192;            \
    _Pragma("unroll") for (int m2 = 0; m2 < 4; ++m2) {               \
      afr[m2][0] = *(const bf16x8*)(_pa + aOff[m2]);                 \
      afr[m2][1] = *(const bf16x8*)(_pa + (aOff[m2] ^ 32));          \
    }                                                                \
  } while (0)

#define READ_B(buf, nh)                                              \
  do {                                                               \
    const bf16* _pb = ldsB + (buf) * 16384 + (nh) * 8192;            \
    _Pragma("unroll") for (int n2 = 0; n2 < 2; ++n2) {               \
      bfr[(nh) * 2 + n2][0] = *(const bf16x8*)(_pb + bOff[(nh) * 2 + n2]);        \
      bfr[(nh) * 2 + n2][1] = *(const bf16x8*)(_pb + (bOff[(nh) * 2 + n2] ^ 32)); \
    }                                                                \
  } while (0)

#define QMFMA(mh, nh)                                                            \
  do {                                                                           \
    __builtin_amdgcn_s_setprio(1);                                               \
    _Pragma("unroll") for (int m2 = 0; m2 < 4; ++m2) {                           \
      _Pragma("unroll") for (int n2 = 0; n2 < 2; ++n2) {                         \
        acc[(mh) * 4 + m2][(nh) * 2 + n2] = __builtin_amdgcn_mfma_f32_16x16x32_bf16( \
            afr[m2][0], bfr[(nh) * 2 + n2][0], acc[(mh) * 4 + m2][(nh) * 2 + n2], 0, 0, 0); \
        acc[(mh) * 4 + m2][(nh) * 2 + n2] = __builtin_amdgcn_mfma_f32_16x16x32_bf16( \
            afr[m2][1], bfr[(nh) * 2 + n2][1], acc[(mh) * 4 + m2][(nh) * 2 + n2], 0, 0, 0); \
      }                                                                          \
    }                                                                            \
    __builtin_amdgcn_s_setprio(0);                                               \
  } while (0)

#define BAR() __builtin_amdgcn_s_barrier()

// ---------- round-4 proven 256x256 kernel (4-phase, vwait<4>, 1 tile deep) ----------
// Epilogues: 0 raw bf16, 1 silu(acc+bias), 2 diff-reduce vs AUX, 3 silu(AUX)*acc.
template <int EPI>
__global__ __launch_bounds__(512, 2) void gemm8p(
    const bf16* __restrict__ A, int lda, long long aZ,
    const bf16* __restrict__ B, int ldb, long long bZ,
    int Kdim,
    unsigned short* __restrict__ C, int ldc, long long cZ,
    const float* __restrict__ bias,
    const bf16* __restrict__ AUX, int ldaux, long long auxZ,
    float* __restrict__ accum,
    int gx, int gxy, int nwg8) {
  extern __shared__ __align__(16) bf16 lds[];
  bf16* ldsA = lds;            // 2 bufs x (2 halves x 128r x 64c) = 32768 elems
  bf16* ldsB = lds + 32768;

  int flat = blockIdx.x;
  int wg = (flat & 7) * nwg8 + (flat >> 3);
  int z = wg / gxy;
  int r0 = wg - z * gxy;
  int by = r0 / gx;
  int bx = r0 - by * gx;
  int rowBase = by * 256, colBase = bx * 256;

  int tid = threadIdx.x;
  int wave = tid >> 6, lane = tid & 63;
  int wr = wave >> 2, wc = wave & 3;

  const bf16* Ab = A + (long long)z * aZ + (long long)rowBase * lda;
  const bf16* Bb = B + (long long)z * bZ + (long long)colBase * ldb;

  int rl = tid >> 3;
  int cg8 = ((tid & 7) ^ (rl & 7)) << 3;
  int srcA = rl * lda + cg8;
  int srcB = rl * ldb + cg8;
  int dstOfs = wave * 512;

  int aOff[4], bOff[4];
#pragma unroll
  for (int m2 = 0; m2 < 4; ++m2) {
    int rA = ((2 * m2 + wr) * 16) + (lane & 15);
    aOff[m2] = rA * 64 + (((lane >> 4) ^ (rA & 7)) << 3);
  }
#pragma unroll
  for (int n = 0; n < 4; ++n) {
    int rB = (((4 * n + wc) * 16) & 127) + (lane & 15);
    bOff[n] = rB * 64 + (((lane >> 4) ^ (rB & 7)) << 3);
  }

  f32x4 acc[8][4] = {};
  bf16x8 afr[4][2], bfr[4][2];

  auto stA = [&](int buf, int hh, int kt) {
    const bf16* s = Ab + (long long)(hh * 128) * lda + kt * 64;
    bf16* d = ldsA + buf * 16384 + hh * 8192 + dstOfs;
    gload16(s + srcA, d);
    gload16(s + srcA + 64 * lda, d + 4096);
  };
  auto stB = [&](int buf, int hh, int kt) {
    const bf16* s = Bb + (long long)(hh * 128) * ldb + kt * 64;
    bf16* d = ldsB + buf * 16384 + hh * 8192 + dstOfs;
    gload16(s + srcB, d);
    gload16(s + srcB + 64 * ldb, d + 4096);
  };

  int NT = Kdim >> 6;
  int cur = 0;

  stA(0, 0, 0); stB(0, 0, 0); stB(0, 1, 0); stA(0, 1, 0);
  vwait<4>();
  BAR();

  for (int t = 0; t < NT - 1; ++t) {
    int nb = cur ^ 1;
    READ_A(cur, 0);
    READ_B(cur, 0);
    stA(nb, 0, t + 1);
    vwait<4>();
    BAR();
    QMFMA(0, 0);
    READ_B(cur, 1);
    stB(nb, 0, t + 1);
    vwait<4>();
    BAR();
    QMFMA(0, 1);
    READ_A(cur, 1);
    stB(nb, 1, t + 1);
    BAR();
    QMFMA(1, 1);
    stA(nb, 1, t + 1);
    vwait<4>();
    BAR();
    QMFMA(1, 0);
    cur = nb;
  }

  READ_A(cur, 0);
  READ_B(cur, 0);
  vwait<2>();
  BAR();
  QMFMA(0, 0);
  READ_B(cur, 1);
  vwait<0>();
  BAR();
  QMFMA(0, 1);
  READ_A(cur, 1);
  QMFMA(1, 1);
  QMFMA(1, 0);

  if constexpr (EPI == 2) {
    const bf16* AUXb = AUX + (long long)z * auxZ;
#pragma unroll
    for (int m = 0; m < 8; ++m) {
#pragma unroll
      for (int r = 0; r < 4; ++r) {
        int row = rowBase + (2 * m + wr) * 16 + ((lane >> 4) << 2) + r;
        float ssq = 0.f, sab = 0.f;
#pragma unroll
        for (int n = 0; n < 4; ++n) {
          int col = colBase + (4 * n + wc) * 16 + (lane & 15);
          float p = acc[m][n][r] + bias[col];
          float d = __bfloat162float(AUXb[(long long)row * ldaux + col]) - p;
          ssq += d * d;
          sab += fabsf(d);
        }
#pragma unroll
        for (int off = 1; off < 16; off <<= 1) {
          ssq += __shfl_xor(ssq, off);
          sab += __shfl_xor(sab, off);
        }
        if ((lane & 15) == 0) {
          atomicAdd(&accum[row], ssq);
          atomicAdd(&accum[BATCH + row], sab);
        }
      }
    }
  } else {
    unsigned short* Cb = C + (long long)z * cZ;
    const bf16* AUXb = (EPI == 3) ? (AUX + (long long)z * auxZ) : nullptr;
#pragma unroll
    for (int m = 0; m < 8; ++m) {
#pragma unroll
      for (int n = 0; n < 4; ++n) {
        int col = colBase + (4 * n + wc) * 16 + (lane & 15);
#pragma unroll
        for (int r = 0; r < 4; ++r) {
          int row = rowBase + (2 * m + wr) * 16 + ((lane >> 4) << 2) + r;
          float v = acc[m][n][r];
          if constexpr (EPI == 1) {
            v += bias[col];
            v = v / (1.f + __expf(-v));
          } else if constexpr (EPI == 3) {
            float s = __bfloat162float(AUXb[(long long)row * ldaux + col]);
            v = v * (s / (1.f + __expf(-s)));
          }
          Cb[(long long)row * ldc + col] = f2bf(v);
        }
      }
    }
  }
}

// ---------- fused dual-B kernel: g = silu(x W1^T) * (x W3^T) ----------
// BM=256, BN=128, BK=64, 8 waves (2x4), 4 phases/K-tile, verify-ahead vwait<4>.
// LDS: A 2x16384 + B1 2x8192 + B3 2x8192 = 65536 elems = 128 KiB.
#define READ_B1(buf)                                                  \
  do {                                                                \
    const bf16* _pb = ldsB1 + (buf) * 8192;                           \
    _Pragma("unroll") for (int n2 = 0; n2 < 2; ++n2) {                \
      b1fr[n2][0] = *(const bf16x8*)(_pb + bOff[n2]);                 \
      b1fr[n2][1] = *(const bf16x8*)(_pb + (bOff[n2] ^ 32));          \
    }                                                                 \
  } while (0)

#define READ_B3(buf)                                                  \
  do {                                                                \
    const bf16* _pb = ldsB3 + (buf) * 8192;                           \
    _Pragma("unroll") for (int n2 = 0; n2 < 2; ++n2) {                \
      b3fr[n2][0] = *(const bf16x8*)(_pb + bOff[n2]);                 \
      b3fr[n2][1] = *(const bf16x8*)(_pb + (bOff[n2] ^ 32));          \
    }                                                                 \
  } while (0)

#define QMFMA_D(ACC, mh, BF)                                                     \
  do {                                                                           \
    __builtin_amdgcn_s_setprio(1);                                               \
    _Pragma("unroll") for (int m2 = 0; m2 < 4; ++m2) {                           \
      _Pragma("unroll") for (int n2 = 0; n2 < 2; ++n2) {                         \
        ACC[(mh) * 4 + m2][n2] = __builtin_amdgcn_mfma_f32_16x16x32_bf16(        \
            afr[m2][0], BF[n2][0], ACC[(mh) * 4 + m2][n2], 0, 0, 0);             \
        ACC[(mh) * 4 + m2][n2] = __builtin_amdgcn_mfma_f32_16x16x32_bf16(        \
            afr[m2][1], BF[n2][1], ACC[(mh) * 4 + m2][n2], 0, 0, 0);             \
      }                                                                          \
    }                                                                            \
    __builtin_amdgcn_s_setprio(0);                                               \
  } while (0)

__global__ __launch_bounds__(512, 2) void gemm_dual(
    const bf16* __restrict__ A,
    const bf16* __restrict__ W1b, const bf16* __restrict__ W3b,
    unsigned short* __restrict__ G,
    int gx, int gxy, int nwg8) {
  extern __shared__ __align__(16) bf16 lds[];
  bf16* ldsA = lds;              // 2 bufs x 16384
  bf16* ldsB1 = lds + 32768;     // 2 bufs x 8192
  bf16* ldsB3 = lds + 49152;     // 2 bufs x 8192

  int flat = blockIdx.x;
  int wg = (flat & 7) * nwg8 + (flat >> 3);
  int z = wg / gxy;
  int r0 = wg - z * gxy;
  int by = r0 / gx;
  int bx = r0 - by * gx;
  int rowBase = by * 256, colBase = bx * 128;

  int tid = threadIdx.x;
  int wave = tid >> 6, lane = tid & 63;
  int wr = wave >> 2, wc = wave & 3;

  const bf16* Ab = A + (long long)rowBase * IN_DIM;
  const bf16* B1b = W1b + (long long)z * OUT_DIM * IN_DIM + (long long)colBase * IN_DIM;
  const bf16* B3b = W3b + (long long)z * OUT_DIM * IN_DIM + (long long)colBase * IN_DIM;

  int rl = tid >> 3;
  int cg8 = ((tid & 7) ^ (rl & 7)) << 3;
  int src = rl * IN_DIM + cg8;
  int dstOfs = wave * 512;

  int aOff[4], bOff[2];
#pragma unroll
  for (int m2 = 0; m2 < 4; ++m2) {
    int rA = ((2 * m2 + wr) * 16) + (lane & 15);
    aOff[m2] = rA * 64 + (((lane >> 4) ^ (rA & 7)) << 3);
  }
#pragma unroll
  for (int n2 = 0; n2 < 2; ++n2) {
    int rB = (4 * n2 + wc) * 16 + (lane & 15);   // 0..127
    bOff[n2] = rB * 64 + (((lane >> 4) ^ (rB & 7)) << 3);
  }

  f32x4 acc1[8][2] = {};
  f32x4 acc2[8][2] = {};
  bf16x8 afr[4][2], b1fr[2][2], b3fr[2][2];

  auto stA = [&](int buf, int hh, int kt) {
    const bf16* s = Ab + (long long)(hh * 128) * IN_DIM + kt * 64;
    bf16* d = ldsA + buf * 16384 + hh * 8192 + dstOfs;
    gload16(s + src, d);
    gload16(s + src + 64 * IN_DIM, d + 4096);
  };
  auto stB1 = [&](int buf, int kt) {
    const bf16* s = B1b + kt * 64;
    bf16* d = ldsB1 + buf * 8192 + dstOfs;
    gload16(s + src, d);
    gload16(s + src + 64 * IN_DIM, d + 4096);
  };
  auto stB3 = [&](int buf, int kt) {
    const bf16* s = B3b + kt * 64;
    bf16* d = ldsB3 + buf * 8192 + dstOfs;
    gload16(s + src, d);
    gload16(s + src + 64 * IN_DIM, d + 4096);
  };

  const int NT = IN_DIM >> 6;
  int cur = 0;

  // prologue: stage [Alo, B1, B3, Ahi] of tile 0; verify Alo+B1
  stA(0, 0, 0); stB1(0, 0); stB3(0, 0); stA(0, 1, 0);
  vwait<4>();
  BAR();

  for (int t = 0; t < NT - 1; ++t) {
    int nb = cur ^ 1;
    // P0: Q1(lo); stage Alo(t+1); verify B3(t)
    READ_A(cur, 0);
    READ_B1(cur);
    stA(nb, 0, t + 1);
    vwait<4>();
    BAR();
    QMFMA_D(acc1, 0, b1fr);
    // P1: Q3(lo); stage B1(t+1); verify Ahi(t)
    READ_B3(cur);
    stB1(nb, t + 1);
    vwait<4>();
    BAR();
    QMFMA_D(acc2, 0, b3fr);
    // P2: Q1(hi); stage B3(t+1); no verify needed
    READ_A(cur, 1);
    stB3(nb, t + 1);
    BAR();
    QMFMA_D(acc1, 1, b1fr);
    // P3: Q3(hi); stage Ahi(t+1); verify Alo(t+1)+B1(t+1)
    stA(nb, 1, t + 1);
    vwait<4>();
    BAR();
    QMFMA_D(acc2, 1, b3fr);
    cur = nb;
  }

  // final tile: drain
  READ_A(cur, 0);
  READ_B1(cur);
  vwait<2>();
  BAR();
  QMFMA_D(acc1, 0, b1fr);
  READ_B3(cur);
  vwait<0>();
  BAR();
  QMFMA_D(acc2, 0, b3fr);
  READ_A(cur, 1);
  QMFMA_D(acc1, 1, b1fr);
  QMFMA_D(acc2, 1, b3fr);

  // epilogue: g = silu(acc1) * acc2
  unsigned short* Gb = G + (long long)z * OUT_DIM;
#pragma unroll
  for (int m = 0; m < 8; ++m) {
#pragma unroll
    for (int n2 = 0; n2 < 2; ++n2) {
      int col = colBase + (4 * n2 + wc) * 16 + (lane & 15);
#pragma unroll
      for (int r = 0; r < 4; ++r) {
        int row = rowBase + (2 * m + wr) * 16 + ((lane >> 4) << 2) + r;
        float v1 = acc1[m][n2][r], v2 = acc2[m][n2][r];
        float g = v2 * (v1 / (1.f + __expf(-v1)));
        Gb[(long long)row * (NEXP * OUT_DIM) + col] = f2bf(g);
      }
    }
  }
}

__global__ void zero_accum(float* a) {
  int i = blockIdx.x * 256 + threadIdx.x;
  if (i < 2 * BATCH) a[i] = 0.f;
}

__global__ void finalize_kernel(const float* __restrict__ accum, float* __restrict__ out) {
  int b = blockIdx.x * 256 + threadIdx.x;
  if (b < BATCH) {
    out[b] = sqrtf(accum[b]);
    out[BATCH + b] = accum[BATCH + b] * (1.f / IN_DIM);
  }
}

extern "C" void kernel_launch(void* const* d_in, const int* in_sizes, int n_in,
                              void* d_out, int out_size, void* d_ws, size_t ws_size,
                              hipStream_t stream) {
  const float* x    = (const float*)d_in[0];
  const float* W1   = (const float*)d_in[1];
  const float* W3   = (const float*)d_in[2];
  const float* W2   = (const float*)d_in[3];
  const float* fc1w = (const float*)d_in[4];
  const float* fc1b = (const float*)d_in[5];
  const float* fc2w = (const float*)d_in[6];
  const float* fc2b = (const float*)d_in[7];
  float* out = (float*)d_out;

  char* ws = (char*)d_ws;
  size_t off = 0;
  auto alloc = [&](size_t bytes) {
    char* p = ws + off;
    off += (bytes + 255) & ~(size_t)255;
    return p;
  };
  bf16* xb   = (bf16*)alloc((size_t)BATCH * IN_DIM * 2);
  bf16* w1b  = (bf16*)alloc((size_t)NEXP * OUT_DIM * IN_DIM * 2);
  bf16* w3b  = (bf16*)alloc((size_t)NEXP * OUT_DIM * IN_DIM * 2);
  bf16* w2b0 = (bf16*)alloc((size_t)IN_DIM * OUT_DIM * 2);
  bf16* w2t  = (bf16*)alloc((size_t)KEXP * OUT_DIM * IN_DIM * 2);
  bf16* f1b  = (bf16*)alloc((size_t)RDIM * IN_DIM * KEXP * 2);
  bf16* f2b  = (bf16*)alloc((size_t)IN_DIM * RDIM * 2);
  bf16* gbuf = (bf16*)alloc((size_t)BATCH * NEXP * OUT_DIM * 2);
  bf16* scratch = (bf16*)alloc((size_t)RDIM * KEXP * OUT_DIM * 2);   // Pcat (R x 8192)
  bf16* o0   = (bf16*)alloc((size_t)BATCH * IN_DIM * 2);
  bf16* hbuf = (bf16*)alloc((size_t)BATCH * RDIM * 2);
  float* accum = (float*)alloc((size_t)2 * BATCH * 4);
  if (off > ws_size) return;

  bf16* Pcat = scratch;

  auto cvt = [&](const float* in, bf16* outp, size_t n) {
    int n8 = (int)(n / 8);
    cvt_kernel<<<(n8 + 255) / 256, 256, 0, stream>>>(in, (unsigned short*)outp, n8);
  };
  cvt(x,    xb,   (size_t)BATCH * IN_DIM);
  cvt(W1,   w1b,  (size_t)NEXP * OUT_DIM * IN_DIM);
  cvt(W3,   w3b,  (size_t)NEXP * OUT_DIM * IN_DIM);
  cvt(W2,   w2b0, (size_t)IN_DIM * OUT_DIM);          // expert 0 (i,o)
  cvt(fc1w, f1b,  (size_t)RDIM * IN_DIM * KEXP);
  cvt(fc2w, f2b,  (size_t)IN_DIM * RDIM);
  // W2[1..4]: (i,o) fp32 -> (o,i) bf16
  tcvt_kernel<<<dim3(OUT_DIM / 32, IN_DIM / 32, KEXP), 256, 0, stream>>>(
      W2 + (size_t)IN_DIM * OUT_DIM, (unsigned short*)w2t, IN_DIM, OUT_DIM);

  const size_t LDSB = 131072;

  // stage 1 (fused): g = silu(x W1^T) * (x W3^T)
  {
    int gx = OUT_DIM / 128, gxy = gx * (BATCH / 256), nwg = gxy * NEXP;  // 16*16*5=1280
    gemm_dual<<<nwg, 512, LDSB, stream>>>(
        xb, w1b, w3b, (unsigned short*)gbuf, gx, gxy, nwg / 8);
  }
  // o0 = g_0 W2[0]^T
  {
    int gx = IN_DIM / 256, gxy = gx * (BATCH / 256), nwg = gxy;
    gemm8p<0><<<nwg, 512, LDSB, stream>>>(
        gbuf, NEXP * OUT_DIM, 0LL,
        w2b0, OUT_DIM, 0LL,
        OUT_DIM,
        (unsigned short*)o0, IN_DIM, 0LL,
        nullptr, nullptr, 0, 0LL, nullptr,
        gx, gxy, nwg / 8);
  }
  // P_k = F_k W2[k]  (R x 2048 each, stored side-by-side in Pcat, ldc 8192)
  {
    int gx = OUT_DIM / 256, gxy = gx * (RDIM / 256), nwg = gxy * KEXP;
    gemm8p<0><<<nwg, 512, LDSB, stream>>>(
        f1b, KEXP * IN_DIM, (long long)IN_DIM,
        w2t, IN_DIM, (long long)OUT_DIM * IN_DIM,
        IN_DIM,
        (unsigned short*)Pcat, KEXP * OUT_DIM, (long long)OUT_DIM,
        nullptr, nullptr, 0, 0LL, nullptr,
        gx, gxy, nwg / 8);
  }
  // fc1': h = silu(g[:,1:,:] Pcat^T + b)   (K = 8192)
  {
    int gx = RDIM / 256, gxy = gx * (BATCH / 256), nwg = gxy;
    gemm8p<1><<<nwg, 512, LDSB, stream>>>(
        gbuf + OUT_DIM, NEXP * OUT_DIM, 0LL,
        Pcat, KEXP * OUT_DIM, 0LL,
        KEXP * OUT_DIM,
        (unsigned short*)hbuf, RDIM, 0LL,
        fc1b, nullptr, 0, 0LL, nullptr,
        gx, gxy, nwg / 8);
  }
  // fc2 + diff-reduce vs o0
  zero_accum<<<(2 * BATCH + 255) / 256, 256, 0, stream>>>(accum);
  {
    int gx = IN_DIM / 256, gxy = gx * (BATCH / 256), nwg = gxy;
    gemm8p<2><<<nwg, 512, LDSB, stream>>>(
        hbuf, RDIM, 0LL,
        f2b, RDIM, 0LL,
        RDIM,
        nullptr, 0, 0LL,
        fc2b, o0, IN_DIM, 0LL, accum,
        gx, gxy, nwg / 8);
  }
  finalize_kernel<<<(BATCH + 255) / 256, 256, 0, stream>>>(accum, out);
}